// Round 8
// baseline (669.293 us; speedup 1.0000x reference)
//
#include <hip/hip_runtime.h>
#include <hip/hip_bf16.h>

typedef __attribute__((ext_vector_type(8))) short short8;
typedef __attribute__((ext_vector_type(4))) float f32x4;
typedef __attribute__((ext_vector_type(4))) int i32x4;
typedef __attribute__((ext_vector_type(2))) int i32x2;
typedef __attribute__((ext_vector_type(4))) unsigned u32x4;

#define NTOK 512
#define NEXP 16
#define TOPK 4
#define HD   2880
#define ID   2880
#define N1   5760   // 2*I
#define NGRP 90     // 32-value groups per row
#define NKT  45     // HD/64 K-steps
#define ROWB 5760   // row byte stride for A sources (HD*2 == ID*2)

__device__ __forceinline__ unsigned perm(unsigned hi, unsigned lo, unsigned sel) {
  return __builtin_amdgcn_perm(hi, lo, sel);
}

// ---------------- perm-LUT MXFP4 dequant (bit-exact bf16, scale folded) ----------------
__device__ __forceinline__ u32x4 dq_word4(unsigned p, unsigned hbl, unsigned hbh,
                                          unsigned lbl, unsigned lbh) {
  unsigned ph = p >> 4;
  unsigned il = p  & 0x07070707u, sl = p  & 0x08080808u;
  unsigned ih = ph & 0x07070707u, sh = ph & 0x08080808u;
  unsigned hbL = perm(hbh, hbl, il) | (sl << 4);
  unsigned lbL = perm(lbh, lbl, il);
  unsigned hbH = perm(hbh, hbl, ih) | (sh << 4);
  unsigned lbH = perm(lbh, lbl, ih);
  unsigned mL01 = perm(hbL, lbL, 0x05010400u);
  unsigned mL23 = perm(hbL, lbL, 0x07030602u);
  unsigned mH01 = perm(hbH, lbH, 0x05010400u);
  unsigned mH23 = perm(hbH, lbH, 0x07030602u);
  u32x4 w;
  w.x = perm(mH01, mL01, 0x05040100u);
  w.y = perm(mH01, mL01, 0x07060302u);
  w.z = perm(mH23, mL23, 0x05040100u);
  w.w = perm(mH23, mL23, 0x07060302u);
  return w;
}

// one B MFMA fragment: 4 widened nibble-bytes (8 values) + per-lane scale -> short8 bf16
__device__ __forceinline__ short8 dq_frag(i32x4 q, int sc) {
  unsigned m7 = (unsigned)((127 - sc) << 7);          // sc in [118,127]
  unsigned mm = m7 | (m7 << 16);
  unsigned e10 = (0x3F00u - m7) << 16;                // entry0 stays exact 0
  unsigned e32 = 0x3FC03F80u - mm;
  unsigned e54 = 0x40404000u - mm;
  unsigned e76 = 0x40C04080u - mm;
  unsigned hbl = perm(e32, e10, 0x07050301u);
  unsigned hbh = perm(e76, e54, 0x07050301u);
  unsigned lbl = perm(e32, e10, 0x06040200u);
  unsigned lbh = perm(e76, e54, 0x06040200u);
  unsigned pk = (unsigned)q.x | ((unsigned)q.y << 8) |
                ((unsigned)q.z << 16) | ((unsigned)q.w << 24);
  u32x4 w = dq_word4(pk, hbl, hbh, lbl, lbh);
  return __builtin_bit_cast(short8, w);
}

// ---------------- RMSNorm (also zeroes cnt; runs before router on the stream) ----------------
__global__ __launch_bounds__(256)
void rmsnorm_k(const float* __restrict__ x, const float* __restrict__ nsc,
               float* __restrict__ tf, __hip_bfloat16* __restrict__ tb,
               int* __restrict__ cnt)
{
  int t = blockIdx.x;
  if (t == 0 && threadIdx.x < NEXP) cnt[threadIdx.x] = 0;
  const float* xr = x + (size_t)t * HD;
  float s = 0.f;
  for (int i = threadIdx.x; i < HD; i += 256) { float v = xr[i]; s += v * v; }
#pragma unroll
  for (int o = 32; o > 0; o >>= 1) s += __shfl_down(s, o);
  __shared__ float red[4];
  if ((threadIdx.x & 63) == 0) red[threadIdx.x >> 6] = s;
  __syncthreads();
  float tot = red[0] + red[1] + red[2] + red[3];
  float rinv = rsqrtf(tot / (float)HD + 1e-5f);
  for (int i = threadIdx.x; i < HD; i += 256) {
    float v = xr[i] * rinv * nsc[i];
    tf[(size_t)t * HD + i] = v;
    tb[(size_t)t * HD + i] = __float2bfloat16(v);
  }
}

// ---------------- Router ----------------
__global__ __launch_bounds__(256)
void router_k(const float* __restrict__ tf, const float* __restrict__ gw,
              const float* __restrict__ gb, float* __restrict__ wpair,
              int* __restrict__ cnt, int* __restrict__ tok_list, int* __restrict__ pair_list)
{
  int t = blockIdx.x;
  int tid = threadIdx.x;
  int e = tid >> 4, l16 = tid & 15;
  const float* tr = tf + (size_t)t * HD;
  float s = 0.f;
  for (int i = l16; i < HD; i += 16) s += tr[i] * gw[e * HD + i];
#pragma unroll
  for (int o = 1; o < 16; o <<= 1) s += __shfl_xor(s, o);
  __shared__ float logits[NEXP];
  if (l16 == 0) logits[e] = s + gb[e];
  __syncthreads();
  if (tid == 0) {
    float v[NEXP];
#pragma unroll
    for (int i = 0; i < NEXP; ++i) v[i] = logits[i];
    int idx[TOPK]; float val[TOPK];
#pragma unroll
    for (int k = 0; k < TOPK; ++k) {
      int bi = 0; float bv = -1e30f;
      for (int i = 0; i < NEXP; ++i) if (v[i] > bv) { bv = v[i]; bi = i; }
      idx[k] = bi; val[k] = bv; v[bi] = -1e30f;
    }
    float mx = val[0], sum = 0.f, w[TOPK];
#pragma unroll
    for (int k = 0; k < TOPK; ++k) { w[k] = __expf(val[k] - mx); sum += w[k]; }
#pragma unroll
    for (int k = 0; k < TOPK; ++k) {
      float wk = w[k] / sum;
      int ee = idx[k];
      int slot = atomicAdd(&cnt[ee], 1);
      tok_list[ee * NTOK + slot]  = t;
      pair_list[ee * NTOK + slot] = t * TOPK + k;
      wpair[t * TOPK + k] = wk;
    }
  }
}

// ---------------- Grouped GEMM: 1-wave blocks, 64M x 64N tile, LDS-free, barrier-free.
// A (bf16, L2-resident) and B (MXFP4, HBM-streamed) load directly into MFMA fragment
// layout. B dequanted in-register (perm-LUT); depth-1 B prefetch with compiler-managed
// waits; A latency hides under the dequant VALU chain; independent waves = free slip.
template<int STAGE>
__global__ __launch_bounds__(64, 2)
void moe_gemm(const __hip_bfloat16* __restrict__ Asrc,
              const int* __restrict__ Bblk, const int* __restrict__ Bscl,
              const float* __restrict__ Bbias,
              const int* __restrict__ cnt,
              const int* __restrict__ tok_list, const int* __restrict__ pair_list,
              __hip_bfloat16* __restrict__ h_out, float* __restrict__ o_out)
{
  constexpr int NDIM = (STAGE == 1) ? N1 : HD;
  const int e  = blockIdx.z;
  const int ne = cnt[e];
  const int m0 = blockIdx.y * 64;
  if (m0 >= ne) return;
  const int n0 = blockIdx.x * 64;
  const int lane = threadIdx.x;
  const int l15 = lane & 15, l4 = lane >> 4;

  const int* glist = (STAGE == 1 ? tok_list : pair_list) + e * NTOK;
  const int* plist = pair_list + e * NTOK;

  // A per-lane byte offsets for 4 m-frags (row = gathered token/pair slot)
  const char* Abase = (const char*)Asrc;
  unsigned aofs[4];
#pragma unroll
  for (int f = 0; f < 4; ++f) {
    int slot = m0 + f * 16 + l15; if (slot > ne - 1) slot = ne - 1;
    aofs[f] = (unsigned)glist[slot] * (unsigned)ROWB + (unsigned)(l4 * 16);
  }
  // B per-lane offsets (int units) for 4 n-frags; NDIM % 64 == 0 -> no clamp needed
  unsigned bofs[4], srow[4];
#pragma unroll
  for (int f = 0; f < 4; ++f) {
    int row = n0 + f * 16 + l15;
    unsigned rb = (unsigned)(e * NDIM + row) * NGRP;
    bofs[f] = rb * 16 + (unsigned)(l4 * 4);   // + (t*2+kk)*16 per K-step
    srow[f] = rb;                             // + 2*t (int2 per K-step)
  }

  f32x4 zero = {0.f, 0.f, 0.f, 0.f};
  f32x4 acc[4][4];
#pragma unroll
  for (int a = 0; a < 4; ++a)
#pragma unroll
    for (int b = 0; b < 4; ++b) acc[a][b] = zero;

  // B current-tile raw fragments + scale pairs (prologue: tile 0)
  i32x4 q[4][2]; i32x2 sc[4];
#pragma unroll
  for (int f = 0; f < 4; ++f) {
#pragma unroll
    for (int kk = 0; kk < 2; ++kk)
      q[f][kk] = *(const i32x4*)(Bblk + bofs[f] + (unsigned)(kk * 16));
    sc[f] = *(const i32x2*)(Bscl + srow[f]);
  }

  for (int t = 0; t < NKT; ++t) {
    // A fragments for tile t (L2-resident; latency covered by dequant below)
    i32x4 a[4][2];
#pragma unroll
    for (int f = 0; f < 4; ++f) {
#pragma unroll
      for (int kk = 0; kk < 2; ++kk)
        a[f][kk] = *(const i32x4*)(Abase + aofs[f] + (unsigned)(t * 128 + kk * 64));
    }

    // prefetch B(t+1) (wrap on last iter: redundant L2-hit load keeps code uniform)
    const int tn = (t + 1 == NKT) ? 0 : t + 1;
    i32x4 p[4][2]; i32x2 ps[4];
#pragma unroll
    for (int f = 0; f < 4; ++f) {
#pragma unroll
      for (int kk = 0; kk < 2; ++kk)
        p[f][kk] = *(const i32x4*)(Bblk + bofs[f] + (unsigned)((tn * 2 + kk) * 16));
      ps[f] = *(const i32x2*)(Bscl + srow[f] + (unsigned)(tn * 2));
    }

    // dequant current B tiles (the long VALU chain that hides A/B load latency)
    short8 b[4][2];
#pragma unroll
    for (int f = 0; f < 4; ++f) {
      b[f][0] = dq_frag(q[f][0], sc[f].x);
      b[f][1] = dq_frag(q[f][1], sc[f].y);
    }

    // MFMA: acc[mf][nf] += A[mf][kk] * B[nf][kk]
    __builtin_amdgcn_s_setprio(1);
#pragma unroll
    for (int kk = 0; kk < 2; ++kk) {
#pragma unroll
      for (int mf = 0; mf < 4; ++mf) {
        short8 af = __builtin_bit_cast(short8, a[mf][kk]);
#pragma unroll
        for (int nf = 0; nf < 4; ++nf)
          acc[mf][nf] = __builtin_amdgcn_mfma_f32_16x16x32_bf16(af, b[nf][kk], acc[mf][nf], 0, 0, 0);
      }
    }
    __builtin_amdgcn_s_setprio(0);

    // rotate prefetched B into current
#pragma unroll
    for (int f = 0; f < 4; ++f) {
      q[f][0] = p[f][0]; q[f][1] = p[f][1]; sc[f] = ps[f];
    }
  }

  // --- epilogue ---
  if (STAGE == 1) {
#pragma unroll
    for (int ma = 0; ma < 4; ++ma) {
#pragma unroll
      for (int nb = 0; nb < 4; ++nb) {
        int ncol = n0 + nb * 16 + l15;
        float bias = Bbias[e * NDIM + ncol];
#pragma unroll
        for (int j = 0; j < 4; ++j) {
          float u  = acc[ma][nb][j] + bias;
          float up = __shfl_xor(u, 1);
          int slot = m0 + ma * 16 + l4 * 4 + j;
          if (!(lane & 1) && slot < ne) {
            float g  = fminf(u, 7.f);
            float lv = fminf(fmaxf(up, -7.f), 7.f);
            float hv = g / (1.f + __expf(-1.702f * g)) * (lv + 1.f);
            h_out[(size_t)plist[slot] * ID + (ncol >> 1)] = __float2bfloat16(hv);
          }
        }
      }
    }
  } else {
#pragma unroll
    for (int ma = 0; ma < 4; ++ma) {
#pragma unroll
      for (int nb = 0; nb < 4; ++nb) {
        int ncol = n0 + nb * 16 + l15;
        float bias = Bbias[e * NDIM + ncol];
#pragma unroll
        for (int j = 0; j < 4; ++j) {
          int slot = m0 + ma * 16 + l4 * 4 + j;
          if (slot < ne)
            o_out[(size_t)plist[slot] * HD + ncol] = acc[ma][nb][j] + bias;
        }
      }
    }
  }
}

// ---------------- Final combine ----------------
__global__ __launch_bounds__(256)
void final_k(const float* __restrict__ x, const float* __restrict__ obuf,
             const float* __restrict__ wpair, float* __restrict__ out)
{
  int t = blockIdx.x;
  float w0 = wpair[t * 4 + 0], w1 = wpair[t * 4 + 1];
  float w2 = wpair[t * 4 + 2], w3 = wpair[t * 4 + 3];
  const float* o0 = obuf + (size_t)(t * 4) * HD;
  for (int i = threadIdx.x; i < HD; i += 256) {
    float r = x[(size_t)t * HD + i]
            + w0 * o0[i] + w1 * o0[HD + i] + w2 * o0[2 * HD + i] + w3 * o0[3 * HD + i];
    out[(size_t)t * HD + i] = r;
  }
}

extern "C" void kernel_launch(void* const* d_in, const int* in_sizes, int n_in,
                              void* d_out, int out_size, void* d_ws, size_t ws_size,
                              hipStream_t stream)
{
  const float* x    = (const float*)d_in[0];
  const float* nsc  = (const float*)d_in[1];
  const float* gw   = (const float*)d_in[2];
  const float* gb   = (const float*)d_in[3];
  const int*   b1   = (const int*)d_in[4];
  const int*   s1   = (const int*)d_in[5];
  const float* bia1 = (const float*)d_in[6];
  const int*   b2   = (const int*)d_in[7];
  const int*   s2   = (const int*)d_in[8];
  const float* bia2 = (const float*)d_in[9];
  float* out = (float*)d_out;

  char* ws = (char*)d_ws;
  size_t off = 0;
  auto alloc = [&](size_t bytes) {
    char* p = ws + off;
    off = (off + bytes + 255) & ~(size_t)255;
    return p;
  };
  float*           tf    = (float*)alloc((size_t)NTOK * HD * 4);
  __hip_bfloat16*  tb    = (__hip_bfloat16*)alloc((size_t)NTOK * HD * 2);
  __hip_bfloat16*  hbuf  = (__hip_bfloat16*)alloc((size_t)NTOK * TOPK * ID * 2);
  float*           obuf  = (float*)alloc((size_t)NTOK * TOPK * HD * 4);
  float*           wpair = (float*)alloc(NTOK * TOPK * 4);
  int*             cnt   = (int*)alloc(64);
  int*             tokl  = (int*)alloc(NEXP * NTOK * 4);
  int*             pairl = (int*)alloc(NEXP * NTOK * 4);

  rmsnorm_k<<<NTOK, 256, 0, stream>>>(x, nsc, tf, tb, cnt);
  router_k<<<NTOK, 256, 0, stream>>>(tf, gw, gb, wpair, cnt, tokl, pairl);
  moe_gemm<1><<<dim3(N1 / 64, 8, NEXP), 64, 0, stream>>>(tb, b1, s1, bia1, cnt, tokl, pairl, hbuf, nullptr);
  moe_gemm<2><<<dim3(HD / 64, 8, NEXP), 64, 0, stream>>>(hbuf, b2, s2, bia2, cnt, tokl, pairl, nullptr, obuf);
  final_k<<<NTOK, 256, 0, stream>>>(x, obuf, wpair, out);
}

// Round 9
// 481.607 us; speedup vs baseline: 1.3897x; 1.3897x over previous
//
#include <hip/hip_runtime.h>
#include <hip/hip_bf16.h>

typedef __attribute__((ext_vector_type(8))) short short8;
typedef __attribute__((ext_vector_type(4))) float f32x4;
typedef __attribute__((ext_vector_type(4))) int i32x4;
typedef __attribute__((ext_vector_type(2))) int i32x2;
typedef __attribute__((ext_vector_type(4))) unsigned u32x4;

#define NTOK 512
#define NEXP 16
#define TOPK 4
#define HD   2880
#define ID   2880
#define N1   5760   // 2*I
#define NGRP 90     // 32-value groups per row
#define NKT  45     // HD/64 K-steps
#define ROWB 5760   // row byte stride (HD*2 == ID*2)

__device__ __forceinline__ unsigned perm(unsigned hi, unsigned lo, unsigned sel) {
  return __builtin_amdgcn_perm(hi, lo, sel);
}

// ---------------- perm-LUT MXFP4 dequant (bit-exact bf16, scale folded) ----------------
__device__ __forceinline__ u32x4 dq_word4(unsigned p, unsigned hbl, unsigned hbh,
                                          unsigned lbl, unsigned lbh) {
  unsigned ph = p >> 4;
  unsigned il = p  & 0x07070707u, sl = p  & 0x08080808u;
  unsigned ih = ph & 0x07070707u, sh = ph & 0x08080808u;
  unsigned hbL = perm(hbh, hbl, il) | (sl << 4);
  unsigned lbL = perm(lbh, lbl, il);
  unsigned hbH = perm(hbh, hbl, ih) | (sh << 4);
  unsigned lbH = perm(lbh, lbl, ih);
  unsigned mL01 = perm(hbL, lbL, 0x05010400u);
  unsigned mL23 = perm(hbL, lbL, 0x07030602u);
  unsigned mH01 = perm(hbH, lbH, 0x05010400u);
  unsigned mH23 = perm(hbH, lbH, 0x07030602u);
  u32x4 w;
  w.x = perm(mH01, mL01, 0x05040100u);
  w.y = perm(mH01, mL01, 0x07060302u);
  w.z = perm(mH23, mL23, 0x05040100u);
  w.w = perm(mH23, mL23, 0x07060302u);
  return w;
}

__device__ __forceinline__ short8 dq_frag(i32x4 q, int sc) {
  unsigned m7 = (unsigned)((127 - sc) << 7);          // sc in [118,127]
  unsigned mm = m7 | (m7 << 16);
  unsigned e10 = (0x3F00u - m7) << 16;                // entry0 stays exact 0
  unsigned e32 = 0x3FC03F80u - mm;
  unsigned e54 = 0x40404000u - mm;
  unsigned e76 = 0x40C04080u - mm;
  unsigned hbl = perm(e32, e10, 0x07050301u);
  unsigned hbh = perm(e76, e54, 0x07050301u);
  unsigned lbl = perm(e32, e10, 0x06040200u);
  unsigned lbh = perm(e76, e54, 0x06040200u);
  unsigned pk = (unsigned)q.x | ((unsigned)q.y << 8) |
                ((unsigned)q.z << 16) | ((unsigned)q.w << 24);
  u32x4 w = dq_word4(pk, hbl, hbh, lbl, lbh);
  return __builtin_bit_cast(short8, w);
}

// ---------------- RMSNorm (also zeroes cnt) ----------------
__global__ __launch_bounds__(256)
void rmsnorm_k(const float* __restrict__ x, const float* __restrict__ nsc,
               float* __restrict__ tf, __hip_bfloat16* __restrict__ tb,
               int* __restrict__ cnt)
{
  int t = blockIdx.x;
  if (t == 0 && threadIdx.x < NEXP) cnt[threadIdx.x] = 0;
  const float* xr = x + (size_t)t * HD;
  float s = 0.f;
  for (int i = threadIdx.x; i < HD; i += 256) { float v = xr[i]; s += v * v; }
#pragma unroll
  for (int o = 32; o > 0; o >>= 1) s += __shfl_down(s, o);
  __shared__ float red[4];
  if ((threadIdx.x & 63) == 0) red[threadIdx.x >> 6] = s;
  __syncthreads();
  float tot = red[0] + red[1] + red[2] + red[3];
  float rinv = rsqrtf(tot / (float)HD + 1e-5f);
  for (int i = threadIdx.x; i < HD; i += 256) {
    float v = xr[i] * rinv * nsc[i];
    tf[(size_t)t * HD + i] = v;
    tb[(size_t)t * HD + i] = __float2bfloat16(v);
  }
}

// ---------------- Router ----------------
__global__ __launch_bounds__(256)
void router_k(const float* __restrict__ tf, const float* __restrict__ gw,
              const float* __restrict__ gb, float* __restrict__ wpair,
              int* __restrict__ cnt, int* __restrict__ tok_list, int* __restrict__ pair_list)
{
  int t = blockIdx.x;
  int tid = threadIdx.x;
  int e = tid >> 4, l16 = tid & 15;
  const float* tr = tf + (size_t)t * HD;
  float s = 0.f;
  for (int i = l16; i < HD; i += 16) s += tr[i] * gw[e * HD + i];
#pragma unroll
  for (int o = 1; o < 16; o <<= 1) s += __shfl_xor(s, o);
  __shared__ float logits[NEXP];
  if (l16 == 0) logits[e] = s + gb[e];
  __syncthreads();
  if (tid == 0) {
    float v[NEXP];
#pragma unroll
    for (int i = 0; i < NEXP; ++i) v[i] = logits[i];
    int idx[TOPK]; float val[TOPK];
#pragma unroll
    for (int k = 0; k < TOPK; ++k) {
      int bi = 0; float bv = -1e30f;
      for (int i = 0; i < NEXP; ++i) if (v[i] > bv) { bv = v[i]; bi = i; }
      idx[k] = bi; val[k] = bv; v[bi] = -1e30f;
    }
    float mx = val[0], sum = 0.f, w[TOPK];
#pragma unroll
    for (int k = 0; k < TOPK; ++k) { w[k] = __expf(val[k] - mx); sum += w[k]; }
#pragma unroll
    for (int k = 0; k < TOPK; ++k) {
      float wk = w[k] / sum;
      int ee = idx[k];
      int slot = atomicAdd(&cnt[ee], 1);
      tok_list[ee * NTOK + slot]  = t;
      pair_list[ee * NTOK + slot] = t * TOPK + k;
      wpair[t * TOPK + k] = wk;
    }
  }
}

#define SYNC_LGKM do { asm volatile("s_waitcnt lgkmcnt(0)" ::: "memory"); \
    __builtin_amdgcn_sched_barrier(0); __builtin_amdgcn_s_barrier(); \
    __builtin_amdgcn_sched_barrier(0); } while (0)
#define SYNC_PLAIN do { __builtin_amdgcn_sched_barrier(0); __builtin_amdgcn_s_barrier(); \
    __builtin_amdgcn_sched_barrier(0); } while (0)

// ---------------- Grouped GEMM: 128M x BN tile, 4 waves (each 128M x BN/4).
// A: reg-staged into 32KB LDS dbuf (line-coalesced loads, XOR-swizzled writes).
// B: direct global->fragment regs, perm-LUT dequant to bf16 carrier b[].
// Raw barriers with lgkm-only drains; every VMEM wait is compiler-counted;
// phase order gives ~1-iter cover for B (HBM) and ~0.7-iter for A (L2).
template<int STAGE, int BN>
__global__ __launch_bounds__(256, 3)
void moe_gemm(const __hip_bfloat16* __restrict__ Asrc,
              const int* __restrict__ Bblk, const int* __restrict__ Bscl,
              const float* __restrict__ Bbias,
              const int* __restrict__ cnt,
              const int* __restrict__ tok_list, const int* __restrict__ pair_list,
              __hip_bfloat16* __restrict__ h_out, float* __restrict__ o_out)
{
  constexpr int NDIM = (STAGE == 1) ? N1 : HD;
  constexpr int NF   = BN / 64;                 // B n-frags per wave (waves split BN 4-way)
  const int e  = blockIdx.z;
  const int ne = cnt[e];
  const int m0 = blockIdx.y * 128;
  if (m0 >= ne) return;
  const int n0 = blockIdx.x * BN;
  const int tid = threadIdx.x;
  const int wave = tid >> 6, lane = tid & 63;
  const int l15 = lane & 15, l4 = lane >> 4;

  __shared__ __align__(16) char Abuf[2][16384];  // [128 rows][128 B] bf16, XOR-swizzled

  const int* glist = (STAGE == 1 ? tok_list : pair_list) + e * NTOK;
  const int* plist = pair_list + e * NTOK;

  // --- A reg-staging: 4 chunks/thread, line-coalesced (8 tids share a row) ---
  const char* agp[4];
  int awoff[4];
#pragma unroll
  for (int c = 0; c < 4; ++c) {
    int g    = c * 256 + tid;          // global 16B-chunk index, 0..1023
    int row  = g >> 3;                 // 8 chunks per 128B row
    int cb   = (g & 7) * 16;           // byte offset within row
    int slot = m0 + row; if (slot > ne - 1) slot = ne - 1;
    agp[c]   = (const char*)Asrc + (size_t)glist[slot] * ROWB + cb;
    awoff[c] = row * 128 + (cb ^ ((row & 7) << 4));
  }

  // --- B per-lane fragment offsets (int units); BN divides NDIM -> no clamp ---
  const int wn = wave * (16 * NF);
  unsigned bofs[NF], srow[NF];
#pragma unroll
  for (int f = 0; f < NF; ++f) {
    int row = n0 + wn + f * 16 + l15;
    unsigned rb = (unsigned)(e * NDIM + row) * NGRP;
    bofs[f] = rb * 16 + (unsigned)(l4 * 4);
    srow[f] = rb;
  }

  // --- A fragment LDS read offsets: 8 m-frags x 2 kk ---
  int aoff[8][2];
#pragma unroll
  for (int mf = 0; mf < 8; ++mf) {
    int row = mf * 16 + l15;
#pragma unroll
    for (int kk = 0; kk < 2; ++kk)
      aoff[mf][kk] = row * 128 + ((kk * 64 + l4 * 16) ^ ((row & 7) << 4));
  }

  f32x4 zero = {0.f, 0.f, 0.f, 0.f};
  f32x4 acc[8][NF];
#pragma unroll
  for (int a = 0; a < 8; ++a)
#pragma unroll
    for (int b = 0; b < NF; ++b) acc[a][b] = zero;

  i32x4 Ar[4];                 // staged A chunks
  i32x4 q[NF][2]; i32x2 sc[NF];  // raw B + scales
  short8 b[NF][2];             // dequanted B carrier (tile t)

  // --- prologue ---
#pragma unroll
  for (int c = 0; c < 4; ++c) Ar[c] = *(const i32x4*)agp[c];          // A(0)
#pragma unroll
  for (int f = 0; f < NF; ++f) {
    q[f][0] = *(const i32x4*)(Bblk + bofs[f]);                         // B(0)
    q[f][1] = *(const i32x4*)(Bblk + bofs[f] + 16);
    sc[f]   = *(const i32x2*)(Bscl + srow[f]);
  }
#pragma unroll
  for (int c = 0; c < 4; ++c) *(i32x4*)(Abuf[0] + awoff[c]) = Ar[c];   // waits A(0)
#pragma unroll
  for (int f = 0; f < NF; ++f) {                                       // waits B(0)
    b[f][0] = dq_frag(q[f][0], sc[f].x);
    b[f][1] = dq_frag(q[f][1], sc[f].y);
  }
#pragma unroll
  for (int c = 0; c < 4; ++c) Ar[c] = *(const i32x4*)(agp[c] + 128);   // A(1)
#pragma unroll
  for (int f = 0; f < NF; ++f) {                                       // B(1)
    q[f][0] = *(const i32x4*)(Bblk + bofs[f] + 2 * 16);
    q[f][1] = *(const i32x4*)(Bblk + bofs[f] + 3 * 16);
    sc[f]   = *(const i32x2*)(Bscl + srow[f] + 2);
  }
  SYNC_LGKM;

  for (int t = 0; t < NKT; ++t) {
    const int cur = t & 1, nxt = cur ^ 1;
    int tld = t + 2; if (tld >= NKT) tld = NKT - 1;   // uniform clamp (dup loads ok)

    // W: stage A(t+1) (Ar) into LDS[nxt]; compiler inserts counted vmcnt wait here
#pragma unroll
    for (int c = 0; c < 4; ++c) *(i32x4*)(Abuf[nxt] + awoff[c]) = Ar[c];
    // I_A: refill Ar with A(tld)
#pragma unroll
    for (int c = 0; c < 4; ++c) Ar[c] = *(const i32x4*)(agp[c] + tld * 128);
    SYNC_LGKM;

    // C: MFMA tile t from LDS[cur] and b(t)
    __builtin_amdgcn_s_setprio(1);
#pragma unroll
    for (int kk = 0; kk < 2; ++kk) {
#pragma unroll
      for (int mf = 0; mf < 8; ++mf) {
        short8 af = *(const short8*)(Abuf[cur] + aoff[mf][kk]);
#pragma unroll
        for (int nf = 0; nf < NF; ++nf)
          acc[mf][nf] = __builtin_amdgcn_mfma_f32_16x16x32_bf16(af, b[nf][kk], acc[mf][nf], 0, 0, 0);
      }
    }
    __builtin_amdgcn_s_setprio(0);

    // D: dequant q (tile t+1) -> b; compiler-counted vmcnt wait, ~1-iter cover
#pragma unroll
    for (int f = 0; f < NF; ++f) {
      b[f][0] = dq_frag(q[f][0], sc[f].x);
      b[f][1] = dq_frag(q[f][1], sc[f].y);
    }
    // I_B: refill q with B(tld)
#pragma unroll
    for (int f = 0; f < NF; ++f) {
      q[f][0] = *(const i32x4*)(Bblk + bofs[f] + (unsigned)((tld * 2 + 0) * 16));
      q[f][1] = *(const i32x4*)(Bblk + bofs[f] + (unsigned)((tld * 2 + 1) * 16));
      sc[f]   = *(const i32x2*)(Bscl + srow[f] + (unsigned)(tld * 2));
    }
    SYNC_PLAIN;
  }

  // --- epilogue ---
  if (STAGE == 1) {
#pragma unroll
    for (int ma = 0; ma < 8; ++ma) {
#pragma unroll
      for (int nb = 0; nb < NF; ++nb) {
        int ncol = n0 + wn + nb * 16 + l15;
        float bias = Bbias[e * NDIM + ncol];
#pragma unroll
        for (int j = 0; j < 4; ++j) {
          float u  = acc[ma][nb][j] + bias;
          float up = __shfl_xor(u, 1);
          int slot = m0 + ma * 16 + l4 * 4 + j;
          if (!(lane & 1) && slot < ne) {
            float g  = fminf(u, 7.f);
            float lv = fminf(fmaxf(up, -7.f), 7.f);
            float hv = g / (1.f + __expf(-1.702f * g)) * (lv + 1.f);
            h_out[(size_t)plist[slot] * ID + (ncol >> 1)] = __float2bfloat16(hv);
          }
        }
      }
    }
  } else {
#pragma unroll
    for (int ma = 0; ma < 8; ++ma) {
#pragma unroll
      for (int nb = 0; nb < NF; ++nb) {
        int ncol = n0 + wn + nb * 16 + l15;
        float bias = Bbias[e * NDIM + ncol];
#pragma unroll
        for (int j = 0; j < 4; ++j) {
          int slot = m0 + ma * 16 + l4 * 4 + j;
          if (slot < ne)
            o_out[(size_t)plist[slot] * HD + ncol] = acc[ma][nb][j] + bias;
        }
      }
    }
  }
}

// ---------------- Final combine ----------------
__global__ __launch_bounds__(256)
void final_k(const float* __restrict__ x, const float* __restrict__ obuf,
             const float* __restrict__ wpair, float* __restrict__ out)
{
  int t = blockIdx.x;
  float w0 = wpair[t * 4 + 0], w1 = wpair[t * 4 + 1];
  float w2 = wpair[t * 4 + 2], w3 = wpair[t * 4 + 3];
  const float* o0 = obuf + (size_t)(t * 4) * HD;
  for (int i = threadIdx.x; i < HD; i += 256) {
    float r = x[(size_t)t * HD + i]
            + w0 * o0[i] + w1 * o0[HD + i] + w2 * o0[2 * HD + i] + w3 * o0[3 * HD + i];
    out[(size_t)t * HD + i] = r;
  }
}

extern "C" void kernel_launch(void* const* d_in, const int* in_sizes, int n_in,
                              void* d_out, int out_size, void* d_ws, size_t ws_size,
                              hipStream_t stream)
{
  const float* x    = (const float*)d_in[0];
  const float* nsc  = (const float*)d_in[1];
  const float* gw   = (const float*)d_in[2];
  const float* gb   = (const float*)d_in[3];
  const int*   b1   = (const int*)d_in[4];
  const int*   s1   = (const int*)d_in[5];
  const float* bia1 = (const float*)d_in[6];
  const int*   b2   = (const int*)d_in[7];
  const int*   s2   = (const int*)d_in[8];
  const float* bia2 = (const float*)d_in[9];
  float* out = (float*)d_out;

  char* ws = (char*)d_ws;
  size_t off = 0;
  auto alloc = [&](size_t bytes) {
    char* p = ws + off;
    off = (off + bytes + 255) & ~(size_t)255;
    return p;
  };
  float*           tf    = (float*)alloc((size_t)NTOK * HD * 4);
  __hip_bfloat16*  tb    = (__hip_bfloat16*)alloc((size_t)NTOK * HD * 2);
  __hip_bfloat16*  hbuf  = (__hip_bfloat16*)alloc((size_t)NTOK * TOPK * ID * 2);
  float*           obuf  = (float*)alloc((size_t)NTOK * TOPK * HD * 4);
  float*           wpair = (float*)alloc(NTOK * TOPK * 4);
  int*             cnt   = (int*)alloc(64);
  int*             tokl  = (int*)alloc(NEXP * NTOK * 4);
  int*             pairl = (int*)alloc(NEXP * NTOK * 4);

  rmsnorm_k<<<NTOK, 256, 0, stream>>>(x, nsc, tf, tb, cnt);
  router_k<<<NTOK, 256, 0, stream>>>(tf, gw, gb, wpair, cnt, tokl, pairl);
  moe_gemm<1, 128><<<dim3(N1 / 128, 4, NEXP), 256, 0, stream>>>(tb, b1, s1, bia1, cnt, tokl, pairl, hbuf, nullptr);
  moe_gemm<2, 64><<<dim3(HD / 64, 4, NEXP), 256, 0, stream>>>(hbuf, b2, s2, bia2, cnt, tokl, pairl, nullptr, obuf);
  final_k<<<NTOK, 256, 0, stream>>>(x, obuf, wpair, out);
}

// Round 10
// 467.567 us; speedup vs baseline: 1.4314x; 1.0300x over previous
//
#include <hip/hip_runtime.h>
#include <hip/hip_bf16.h>

typedef __attribute__((ext_vector_type(8))) short short8;
typedef __attribute__((ext_vector_type(4))) float f32x4;
typedef __attribute__((ext_vector_type(4))) int i32x4;
typedef __attribute__((ext_vector_type(2))) int i32x2;
typedef __attribute__((ext_vector_type(4))) unsigned u32x4;

#define NTOK 512
#define NEXP 16
#define TOPK 4
#define HD   2880
#define ID   2880
#define N1   5760   // 2*I
#define NGRP 90     // 32-value groups per row
#define NKT  45     // HD/64 K-steps
#define ROWB 5760   // row byte stride (HD*2 == ID*2)

__device__ __forceinline__ unsigned perm(unsigned hi, unsigned lo, unsigned sel) {
  return __builtin_amdgcn_perm(hi, lo, sel);
}

// ---------------- perm-LUT MXFP4 dequant (bit-exact bf16, scale folded) ----------------
__device__ __forceinline__ u32x4 dq_word4(unsigned p, unsigned hbl, unsigned hbh,
                                          unsigned lbl, unsigned lbh) {
  unsigned ph = p >> 4;
  unsigned il = p  & 0x07070707u, sl = p  & 0x08080808u;
  unsigned ih = ph & 0x07070707u, sh = ph & 0x08080808u;
  unsigned hbL = perm(hbh, hbl, il) | (sl << 4);
  unsigned lbL = perm(lbh, lbl, il);
  unsigned hbH = perm(hbh, hbl, ih) | (sh << 4);
  unsigned lbH = perm(lbh, lbl, ih);
  unsigned mL01 = perm(hbL, lbL, 0x05010400u);
  unsigned mL23 = perm(hbL, lbL, 0x07030602u);
  unsigned mH01 = perm(hbH, lbH, 0x05010400u);
  unsigned mH23 = perm(hbH, lbH, 0x07030602u);
  u32x4 w;
  w.x = perm(mH01, mL01, 0x05040100u);
  w.y = perm(mH01, mL01, 0x07060302u);
  w.z = perm(mH23, mL23, 0x05040100u);
  w.w = perm(mH23, mL23, 0x07060302u);
  return w;
}

__device__ __forceinline__ short8 dq_frag(i32x4 q, int sc) {
  unsigned m7 = (unsigned)((127 - sc) << 7);          // sc in [118,127]
  unsigned mm = m7 | (m7 << 16);
  unsigned e10 = (0x3F00u - m7) << 16;                // entry0 stays exact 0
  unsigned e32 = 0x3FC03F80u - mm;
  unsigned e54 = 0x40404000u - mm;
  unsigned e76 = 0x40C04080u - mm;
  unsigned hbl = perm(e32, e10, 0x07050301u);
  unsigned hbh = perm(e76, e54, 0x07050301u);
  unsigned lbl = perm(e32, e10, 0x06040200u);
  unsigned lbh = perm(e76, e54, 0x06040200u);
  unsigned pk = (unsigned)q.x | ((unsigned)q.y << 8) |
                ((unsigned)q.z << 16) | ((unsigned)q.w << 24);
  u32x4 w = dq_word4(pk, hbl, hbh, lbl, lbh);
  return __builtin_bit_cast(short8, w);
}

// ---------------- RMSNorm (also zeroes cnt) ----------------
__global__ __launch_bounds__(256)
void rmsnorm_k(const float* __restrict__ x, const float* __restrict__ nsc,
               float* __restrict__ tf, __hip_bfloat16* __restrict__ tb,
               int* __restrict__ cnt)
{
  int t = blockIdx.x;
  if (t == 0 && threadIdx.x < NEXP) cnt[threadIdx.x] = 0;
  const float* xr = x + (size_t)t * HD;
  float s = 0.f;
  for (int i = threadIdx.x; i < HD; i += 256) { float v = xr[i]; s += v * v; }
#pragma unroll
  for (int o = 32; o > 0; o >>= 1) s += __shfl_down(s, o);
  __shared__ float red[4];
  if ((threadIdx.x & 63) == 0) red[threadIdx.x >> 6] = s;
  __syncthreads();
  float tot = red[0] + red[1] + red[2] + red[3];
  float rinv = rsqrtf(tot / (float)HD + 1e-5f);
  for (int i = threadIdx.x; i < HD; i += 256) {
    float v = xr[i] * rinv * nsc[i];
    tf[(size_t)t * HD + i] = v;
    tb[(size_t)t * HD + i] = __float2bfloat16(v);
  }
}

// ---------------- Router ----------------
__global__ __launch_bounds__(256)
void router_k(const float* __restrict__ tf, const float* __restrict__ gw,
              const float* __restrict__ gb, float* __restrict__ wpair,
              int* __restrict__ cnt, int* __restrict__ tok_list, int* __restrict__ pair_list)
{
  int t = blockIdx.x;
  int tid = threadIdx.x;
  int e = tid >> 4, l16 = tid & 15;
  const float* tr = tf + (size_t)t * HD;
  float s = 0.f;
  for (int i = l16; i < HD; i += 16) s += tr[i] * gw[e * HD + i];
#pragma unroll
  for (int o = 1; o < 16; o <<= 1) s += __shfl_xor(s, o);
  __shared__ float logits[NEXP];
  if (l16 == 0) logits[e] = s + gb[e];
  __syncthreads();
  if (tid == 0) {
    float v[NEXP];
#pragma unroll
    for (int i = 0; i < NEXP; ++i) v[i] = logits[i];
    int idx[TOPK]; float val[TOPK];
#pragma unroll
    for (int k = 0; k < TOPK; ++k) {
      int bi = 0; float bv = -1e30f;
      for (int i = 0; i < NEXP; ++i) if (v[i] > bv) { bv = v[i]; bi = i; }
      idx[k] = bi; val[k] = bv; v[bi] = -1e30f;
    }
    float mx = val[0], sum = 0.f, w[TOPK];
#pragma unroll
    for (int k = 0; k < TOPK; ++k) { w[k] = __expf(val[k] - mx); sum += w[k]; }
#pragma unroll
    for (int k = 0; k < TOPK; ++k) {
      float wk = w[k] / sum;
      int ee = idx[k];
      int slot = atomicAdd(&cnt[ee], 1);
      tok_list[ee * NTOK + slot]  = t;
      pair_list[ee * NTOK + slot] = t * TOPK + k;
      wpair[t * TOPK + k] = wk;
    }
  }
}

#define SYNC_LGKM do { asm volatile("s_waitcnt lgkmcnt(0)" ::: "memory"); \
    __builtin_amdgcn_sched_barrier(0); __builtin_amdgcn_s_barrier(); \
    __builtin_amdgcn_sched_barrier(0); } while (0)
#define SYNC_PLAIN do { __builtin_amdgcn_sched_barrier(0); __builtin_amdgcn_s_barrier(); \
    __builtin_amdgcn_sched_barrier(0); } while (0)

// ---------------- Grouped GEMM: 128M x BN tile, 4 waves (each 128M x BN/4).
// A: reg-staged into 32KB LDS dbuf (line-coalesced loads, XOR-swizzled writes).
// B: direct global->fragment regs, perm-LUT dequant to bf16 carrier b[].
// Raw barriers with lgkm-only drains; every VMEM wait is compiler-counted;
// phase order gives ~1-iter cover for both A (L2) and B (HBM).
// BN=64 -> NF=1 -> small VGPR -> 4 blocks/CU residency for TLP.
template<int STAGE, int BN>
__global__ __launch_bounds__(256, 4)
void moe_gemm(const __hip_bfloat16* __restrict__ Asrc,
              const int* __restrict__ Bblk, const int* __restrict__ Bscl,
              const float* __restrict__ Bbias,
              const int* __restrict__ cnt,
              const int* __restrict__ tok_list, const int* __restrict__ pair_list,
              __hip_bfloat16* __restrict__ h_out, float* __restrict__ o_out)
{
  constexpr int NDIM = (STAGE == 1) ? N1 : HD;
  constexpr int NF   = BN / 64;                 // B n-frags per wave (waves split BN 4-way)
  const int e  = blockIdx.z;
  const int ne = cnt[e];
  const int m0 = blockIdx.y * 128;
  if (m0 >= ne) return;
  const int n0 = blockIdx.x * BN;
  const int tid = threadIdx.x;
  const int wave = tid >> 6, lane = tid & 63;
  const int l15 = lane & 15, l4 = lane >> 4;

  __shared__ __align__(16) char Abuf[2][16384];  // [128 rows][128 B] bf16, XOR-swizzled

  const int* glist = (STAGE == 1 ? tok_list : pair_list) + e * NTOK;
  const int* plist = pair_list + e * NTOK;

  // --- A reg-staging: 4 chunks/thread, line-coalesced (8 tids share a row) ---
  const char* agp[4];
  int awoff[4];
#pragma unroll
  for (int c = 0; c < 4; ++c) {
    int g    = c * 256 + tid;          // global 16B-chunk index, 0..1023
    int row  = g >> 3;                 // 8 chunks per 128B row
    int cb   = (g & 7) * 16;           // byte offset within row
    int slot = m0 + row; if (slot > ne - 1) slot = ne - 1;
    agp[c]   = (const char*)Asrc + (size_t)glist[slot] * ROWB + cb;
    awoff[c] = row * 128 + (cb ^ ((row & 7) << 4));
  }

  // --- B per-lane fragment offsets (int units); BN divides NDIM -> no clamp ---
  const int wn = wave * (16 * NF);
  unsigned bofs[NF], srow[NF];
#pragma unroll
  for (int f = 0; f < NF; ++f) {
    int row = n0 + wn + f * 16 + l15;
    unsigned rb = (unsigned)(e * NDIM + row) * NGRP;
    bofs[f] = rb * 16 + (unsigned)(l4 * 4);
    srow[f] = rb;
  }

  // --- A fragment LDS read offsets: 8 m-frags x 2 kk ---
  int aoff[8][2];
#pragma unroll
  for (int mf = 0; mf < 8; ++mf) {
    int row = mf * 16 + l15;
#pragma unroll
    for (int kk = 0; kk < 2; ++kk)
      aoff[mf][kk] = row * 128 + ((kk * 64 + l4 * 16) ^ ((row & 7) << 4));
  }

  f32x4 zero = {0.f, 0.f, 0.f, 0.f};
  f32x4 acc[8][NF];
#pragma unroll
  for (int a = 0; a < 8; ++a)
#pragma unroll
    for (int b = 0; b < NF; ++b) acc[a][b] = zero;

  i32x4 Ar[4];                   // staged A chunks
  i32x4 q[NF][2]; i32x2 sc[NF];  // raw B + scales
  short8 b[NF][2];               // dequanted B carrier (tile t)

  // --- prologue ---
#pragma unroll
  for (int c = 0; c < 4; ++c) Ar[c] = *(const i32x4*)agp[c];          // A(0)
#pragma unroll
  for (int f = 0; f < NF; ++f) {
    q[f][0] = *(const i32x4*)(Bblk + bofs[f]);                         // B(0)
    q[f][1] = *(const i32x4*)(Bblk + bofs[f] + 16);
    sc[f]   = *(const i32x2*)(Bscl + srow[f]);
  }
#pragma unroll
  for (int c = 0; c < 4; ++c) *(i32x4*)(Abuf[0] + awoff[c]) = Ar[c];   // waits A(0)
#pragma unroll
  for (int f = 0; f < NF; ++f) {                                       // waits B(0)
    b[f][0] = dq_frag(q[f][0], sc[f].x);
    b[f][1] = dq_frag(q[f][1], sc[f].y);
  }
#pragma unroll
  for (int c = 0; c < 4; ++c) Ar[c] = *(const i32x4*)(agp[c] + 128);   // A(1)
#pragma unroll
  for (int f = 0; f < NF; ++f) {                                       // B(1)
    q[f][0] = *(const i32x4*)(Bblk + bofs[f] + 2 * 16);
    q[f][1] = *(const i32x4*)(Bblk + bofs[f] + 3 * 16);
    sc[f]   = *(const i32x2*)(Bscl + srow[f] + 2);
  }
  SYNC_LGKM;

  for (int t = 0; t < NKT; ++t) {
    const int cur = t & 1, nxt = cur ^ 1;
    int tld = t + 2; if (tld >= NKT) tld = NKT - 1;   // uniform clamp (dup loads ok)

    // W: stage A(t+1) (Ar) into LDS[nxt]; compiler inserts counted vmcnt wait here
#pragma unroll
    for (int c = 0; c < 4; ++c) *(i32x4*)(Abuf[nxt] + awoff[c]) = Ar[c];
    // I_A: refill Ar with A(tld)
#pragma unroll
    for (int c = 0; c < 4; ++c) Ar[c] = *(const i32x4*)(agp[c] + tld * 128);
    SYNC_LGKM;

    // C: MFMA tile t from LDS[cur] and b(t)
    __builtin_amdgcn_s_setprio(1);
#pragma unroll
    for (int kk = 0; kk < 2; ++kk) {
#pragma unroll
      for (int mf = 0; mf < 8; ++mf) {
        short8 af = *(const short8*)(Abuf[cur] + aoff[mf][kk]);
#pragma unroll
        for (int nf = 0; nf < NF; ++nf)
          acc[mf][nf] = __builtin_amdgcn_mfma_f32_16x16x32_bf16(af, b[nf][kk], acc[mf][nf], 0, 0, 0);
      }
    }
    __builtin_amdgcn_s_setprio(0);

    // D: dequant q (tile t+1) -> b; compiler-counted vmcnt wait, ~1-iter cover
#pragma unroll
    for (int f = 0; f < NF; ++f) {
      b[f][0] = dq_frag(q[f][0], sc[f].x);
      b[f][1] = dq_frag(q[f][1], sc[f].y);
    }
    // I_B: refill q with B(tld)
#pragma unroll
    for (int f = 0; f < NF; ++f) {
      q[f][0] = *(const i32x4*)(Bblk + bofs[f] + (unsigned)((tld * 2 + 0) * 16));
      q[f][1] = *(const i32x4*)(Bblk + bofs[f] + (unsigned)((tld * 2 + 1) * 16));
      sc[f]   = *(const i32x2*)(Bscl + srow[f] + (unsigned)(tld * 2));
    }
    SYNC_PLAIN;
  }

  // --- epilogue ---
  if (STAGE == 1) {
#pragma unroll
    for (int ma = 0; ma < 8; ++ma) {
#pragma unroll
      for (int nb = 0; nb < NF; ++nb) {
        int ncol = n0 + wn + nb * 16 + l15;
        float bias = Bbias[e * NDIM + ncol];
#pragma unroll
        for (int j = 0; j < 4; ++j) {
          float u  = acc[ma][nb][j] + bias;
          float up = __shfl_xor(u, 1);
          int slot = m0 + ma * 16 + l4 * 4 + j;
          if (!(lane & 1) && slot < ne) {
            float g  = fminf(u, 7.f);
            float lv = fminf(fmaxf(up, -7.f), 7.f);
            float hv = g / (1.f + __expf(-1.702f * g)) * (lv + 1.f);
            h_out[(size_t)plist[slot] * ID + (ncol >> 1)] = __float2bfloat16(hv);
          }
        }
      }
    }
  } else {
#pragma unroll
    for (int ma = 0; ma < 8; ++ma) {
#pragma unroll
      for (int nb = 0; nb < NF; ++nb) {
        int ncol = n0 + wn + nb * 16 + l15;
        float bias = Bbias[e * NDIM + ncol];
#pragma unroll
        for (int j = 0; j < 4; ++j) {
          int slot = m0 + ma * 16 + l4 * 4 + j;
          if (slot < ne)
            o_out[(size_t)plist[slot] * HD + ncol] = acc[ma][nb][j] + bias;
        }
      }
    }
  }
}

// ---------------- Final combine ----------------
__global__ __launch_bounds__(256)
void final_k(const float* __restrict__ x, const float* __restrict__ obuf,
             const float* __restrict__ wpair, float* __restrict__ out)
{
  int t = blockIdx.x;
  float w0 = wpair[t * 4 + 0], w1 = wpair[t * 4 + 1];
  float w2 = wpair[t * 4 + 2], w3 = wpair[t * 4 + 3];
  const float* o0 = obuf + (size_t)(t * 4) * HD;
  for (int i = threadIdx.x; i < HD; i += 256) {
    float r = x[(size_t)t * HD + i]
            + w0 * o0[i] + w1 * o0[HD + i] + w2 * o0[2 * HD + i] + w3 * o0[3 * HD + i];
    out[(size_t)t * HD + i] = r;
  }
}

extern "C" void kernel_launch(void* const* d_in, const int* in_sizes, int n_in,
                              void* d_out, int out_size, void* d_ws, size_t ws_size,
                              hipStream_t stream)
{
  const float* x    = (const float*)d_in[0];
  const float* nsc  = (const float*)d_in[1];
  const float* gw   = (const float*)d_in[2];
  const float* gb   = (const float*)d_in[3];
  const int*   b1   = (const int*)d_in[4];
  const int*   s1   = (const int*)d_in[5];
  const float* bia1 = (const float*)d_in[6];
  const int*   b2   = (const int*)d_in[7];
  const int*   s2   = (const int*)d_in[8];
  const float* bia2 = (const float*)d_in[9];
  float* out = (float*)d_out;

  char* ws = (char*)d_ws;
  size_t off = 0;
  auto alloc = [&](size_t bytes) {
    char* p = ws + off;
    off = (off + bytes + 255) & ~(size_t)255;
    return p;
  };
  float*           tf    = (float*)alloc((size_t)NTOK * HD * 4);
  __hip_bfloat16*  tb    = (__hip_bfloat16*)alloc((size_t)NTOK * HD * 2);
  __hip_bfloat16*  hbuf  = (__hip_bfloat16*)alloc((size_t)NTOK * TOPK * ID * 2);
  float*           obuf  = (float*)alloc((size_t)NTOK * TOPK * HD * 4);
  float*           wpair = (float*)alloc(NTOK * TOPK * 4);
  int*             cnt   = (int*)alloc(64);
  int*             tokl  = (int*)alloc(NEXP * NTOK * 4);
  int*             pairl = (int*)alloc(NEXP * NTOK * 4);

  rmsnorm_k<<<NTOK, 256, 0, stream>>>(x, nsc, tf, tb, cnt);
  router_k<<<NTOK, 256, 0, stream>>>(tf, gw, gb, wpair, cnt, tokl, pairl);
  moe_gemm<1, 64><<<dim3(N1 / 64, 4, NEXP), 256, 0, stream>>>(tb, b1, s1, bia1, cnt, tokl, pairl, hbuf, nullptr);
  moe_gemm<2, 64><<<dim3(HD / 64, 4, NEXP), 256, 0, stream>>>(hbuf, b2, s2, bia2, cnt, tokl, pairl, nullptr, obuf);
  final_k<<<NTOK, 256, 0, stream>>>(x, obuf, wpair, out);
}